// Round 4
// baseline (787.885 us; speedup 1.0000x reference)
//
#include <hip/hip_runtime.h>

// Problem constants: B=4, S=4096, H=1024, R=16
#define BQ 4
#define SQ 4096
#define HQ 1024
#define RQ 16
#define NROWS (BQ * SQ)   // 16384

typedef float vfloat4 __attribute__((ext_vector_type(4)));

// ---------------------------------------------------------------------------
// besum[h] = sum_r be[r][h]
// ---------------------------------------------------------------------------
__global__ void besum_kernel(const float* __restrict__ be, float* __restrict__ besum) {
    int h = blockIdx.x * 256 + threadIdx.x;
    float s = 0.f;
#pragma unroll
    for (int r = 0; r < RQ; ++r) s += be[r * HQ + h];
    besum[h] = s;
}

// ---------------------------------------------------------------------------
// proj: [16384 x 1024] x [1024 x 33] -> SoA P[16][N], U[16][N], V[N].
// 32-row tiles, 512 threads = 8 waves, grid 512 = 2 blocks/CU.
// Wave w owns 4 output cols; lane&31 = row, lane>>5 = K-half (j 0-7 vs 8-15
// of each 64-float K-chunk); halves combined with shfl_xor(32) at the end.
// LDS: 32x64 f32 tile double-buffered (16 KB), chunk^row&7 XOR swizzle.
// Next tile's global load issued before the barrier (latency hides under
// the 128-FMA compute phase). Epilogue folds (dot+bc)*strength into P.
// SoA stores: 128 B contiguous per column -> no partial-line amplification.
// ---------------------------------------------------------------------------
__global__ void __launch_bounds__(512, 4)
proj_kernel(const float* __restrict__ hs, const float* __restrict__ wc,
            const float* __restrict__ we, const float* __restrict__ besum,
            const float* __restrict__ bc, const float* __restrict__ strength,
            float* __restrict__ P, float* __restrict__ U, float* __restrict__ V) {
    __shared__ float lds[2][32 * 64];   // 16 KB
    const int tid = threadIdx.x;
    const int lane = tid & 63;
    const int wave = __builtin_amdgcn_readfirstlane(tid >> 6);
    const int row = lane & 31;
    const int kh = lane >> 5;        // K-half: j = kh*8 + jj
    const int R0 = blockIdx.x * 32;
    const int c0 = wave * 4;
    const float* wbase = (c0 < 16) ? (wc + c0 * HQ) : (we + (c0 - 16) * HQ);
    const int joff = 4 * (kh * 8);   // float offset of this half's j-range

    // Stage geometry: tile = 32 rows x 16 float4-chunks = 512 chunks,
    // 512 threads -> one chunk each, fully coalesced.
    const int r0s = tid >> 4;
    const int m0s = tid & 15;
    const int l0 = r0s * 64 + ((m0s ^ (r0s & 7)) << 2);
    const size_t g0 = (size_t)(R0 + r0s) * HQ + (m0s << 2);
    const int e = row & 7;

    float acc0 = 0.f, acc1 = 0.f, acc2 = 0.f, acc3 = 0.f, vacc = 0.f;

    float4 sa = *(const float4*)(hs + g0);

    for (int kc = 0; kc < 16; ++kc) {
        const int k0 = kc * 64;
        float* buf = lds[kc & 1];
        *(float4*)&buf[l0] = sa;
        if (kc < 15) {  // early-issue next tile
            sa = *(const float4*)(hs + g0 + k0 + 64);
        }
        __syncthreads();  // tile staged
#pragma unroll
        for (int jj = 0; jj < 8; ++jj) {
            const int jf = joff + 4 * jj;   // per-half float offset in chunk
            float4 w0 = *(const float4*)(wbase + 0 * HQ + k0 + jf);
            float4 w1 = *(const float4*)(wbase + 1 * HQ + k0 + jf);
            float4 w2 = *(const float4*)(wbase + 2 * HQ + k0 + jf);
            float4 w3 = *(const float4*)(wbase + 3 * HQ + k0 + jf);
            // swizzled read: slot (j^e) of row holds global chunk j
            const int j = kh * 8 + jj;
            const float4 h = *(const float4*)&buf[row * 64 + ((j ^ e) << 2)];
            acc0 = fmaf(h.x, w0.x, fmaf(h.y, w0.y, fmaf(h.z, w0.z, fmaf(h.w, w0.w, acc0))));
            acc1 = fmaf(h.x, w1.x, fmaf(h.y, w1.y, fmaf(h.z, w1.z, fmaf(h.w, w1.w, acc1))));
            acc2 = fmaf(h.x, w2.x, fmaf(h.y, w2.y, fmaf(h.z, w2.z, fmaf(h.w, w2.w, acc2))));
            acc3 = fmaf(h.x, w3.x, fmaf(h.y, w3.y, fmaf(h.z, w3.z, fmaf(h.w, w3.w, acc3))));
            if (wave == 0) {
                float4 b4 = *(const float4*)(besum + k0 + jf);
                vacc = fmaf(h.x, b4.x, fmaf(h.y, b4.y, fmaf(h.z, b4.z, fmaf(h.w, b4.w, vacc))));
            }
        }
        __syncthreads();  // all reads of buf done before next write to it
    }

    // combine K-halves across lane 32-split
    acc0 += __shfl_xor(acc0, 32);
    acc1 += __shfl_xor(acc1, 32);
    acc2 += __shfl_xor(acc2, 32);
    acc3 += __shfl_xor(acc3, 32);
    if (wave == 0) vacc += __shfl_xor(vacc, 32);

    if (lane < 32) {
        const int r = R0 + row;
        if (wave < 4) {  // P cols c0..c0+3, affine folded
            const float4 st = *(const float4*)(strength + c0);
            const float4 b4 = *(const float4*)(bc + c0);
            P[(c0 + 0) * NROWS + r] = (acc0 + b4.x) * st.x;
            P[(c0 + 1) * NROWS + r] = (acc1 + b4.y) * st.y;
            P[(c0 + 2) * NROWS + r] = (acc2 + b4.z) * st.z;
            P[(c0 + 3) * NROWS + r] = (acc3 + b4.w) * st.w;
            if (wave == 0) V[r] = vacc;
        } else {         // U cols
            const int u0 = c0 - 16;
            U[(u0 + 0) * NROWS + r] = acc0;
            U[(u0 + 1) * NROWS + r] = acc1;
            U[(u0 + 2) * NROWS + r] = acc2;
            U[(u0 + 3) * NROWS + r] = acc3;
        }
    }
}

// ---------------------------------------------------------------------------
// bias[b,s,t] = sum_k P[k][b*S+s]*U[k][b*S+t] + V[b*S+t]
// 128x128 tile / block, 256 threads, 8sx8t per thread.
// SoA global reads (512 B contiguous per k), re-interleaved into LDS:
//   Pl[s][16]: element k at chunk (k>>2)^((s>>3)&3), pos k&3.
//              Read slot kq^(ty&3): 4 addrs/wave, 16-lane broadcast = free.
//   Ul[t][32]: chunk ((k>>2)^((t>>3)&3)) + 4*((t>>5)&1).
//              Read slot 3-bit fn of tx: 8 groups x2 lanes       = free.
// Register schedule: u[8] held per kq, p loaded per i -> no spill.
// Stores: nontemporal float4, 512 B contiguous per 16-lane phase.
// ---------------------------------------------------------------------------
__global__ void __launch_bounds__(256, 3)
bias_kernel(const float* __restrict__ P, const float* __restrict__ U,
            const float* __restrict__ V, float* __restrict__ out) {
    __shared__ float Pl[128 * 16];   // 8 KB
    __shared__ float Ul[128 * 32];   // 16 KB
    __shared__ float Vl[128];
    const int b = blockIdx.z;
    const int tid = threadIdx.x;
    const int t0b = blockIdx.x * 128;
    const int s0b = blockIdx.y * 128;
    const size_t rbase = (size_t)b * SQ;

    // ---- stage: issue all global loads first (T14), then LDS writes ----
    float4 pv[2], uv[2], vv;
#pragma unroll
    for (int kp = 0; kp < 2; ++kp) {
        int idx = kp * 256 + tid;           // 0..511
        int k = idx >> 5, c = idx & 31;     // k row, float4 chunk of 128-wide tile
        pv[kp] = *(const float4*)(P + (size_t)k * NROWS + rbase + s0b + 4 * c);
        uv[kp] = *(const float4*)(U + (size_t)k * NROWS + rbase + t0b + 4 * c);
    }
    if (tid < 32) vv = *(const float4*)(V + rbase + t0b + 4 * tid);

#pragma unroll
    for (int kp = 0; kp < 2; ++kp) {
        int idx = kp * 256 + tid;
        int k = idx >> 5, c = idx & 31;
        int kq = k >> 2, pos = k & 3;
        const float pe[4] = {pv[kp].x, pv[kp].y, pv[kp].z, pv[kp].w};
        const float ue[4] = {uv[kp].x, uv[kp].y, uv[kp].z, uv[kp].w};
#pragma unroll
        for (int ee = 0; ee < 4; ++ee) {
            int loc = 4 * c + ee;
            int slp = kq ^ ((loc >> 3) & 3);
            Pl[loc * 16 + slp * 4 + pos] = pe[ee];
            int slu = (kq ^ ((loc >> 3) & 3)) + 4 * ((loc >> 5) & 1);
            Ul[loc * 32 + slu * 4 + pos] = ue[ee];
        }
    }
    if (tid < 32) *(float4*)&Vl[4 * tid] = vv;
    __syncthreads();

    const int tx = tid & 15, ty = tid >> 4;
    const int ss = ty * 8, ts = tx * 8;

    float acc[8][8] = {{0.f}};
#pragma unroll
    for (int kq = 0; kq < 4; ++kq) {
        float4 u[8];
#pragma unroll
        for (int j = 0; j < 8; ++j) {
            int t = ts + j;
            int slu = (kq ^ (tx & 3)) + 4 * ((tx >> 2) & 1);
            u[j] = *(const float4*)&Ul[t * 32 + slu * 4];
        }
#pragma unroll
        for (int i = 0; i < 8; ++i) {
            // FIX: write slot was kq ^ ((s>>3)&3) with s = ty*8+i -> slot is
            // kq ^ (ty & 3), NOT kq ^ ty (ty reaches 15 -> OOB slot = garbage)
            const float4 p = *(const float4*)&Pl[(ss + i) * 16 + (kq ^ (ty & 3)) * 4];
#pragma unroll
            for (int j = 0; j < 8; ++j)
                acc[i][j] = fmaf(p.x, u[j].x, fmaf(p.y, u[j].y,
                            fmaf(p.z, u[j].z, fmaf(p.w, u[j].w, acc[i][j]))));
        }
    }

    float v[8];
#pragma unroll
    for (int j = 0; j < 8; ++j) v[j] = Vl[ts + j];
#pragma unroll
    for (int i = 0; i < 8; ++i) {
        vfloat4 o0, o1;
        o0.x = acc[i][0] + v[0];
        o0.y = acc[i][1] + v[1];
        o0.z = acc[i][2] + v[2];
        o0.w = acc[i][3] + v[3];
        o1.x = acc[i][4] + v[4];
        o1.y = acc[i][5] + v[5];
        o1.z = acc[i][6] + v[6];
        o1.w = acc[i][7] + v[7];
        const size_t ob = (rbase + s0b + ss + i) * SQ + t0b + ts;
        __builtin_nontemporal_store(o0, (vfloat4*)(out + ob));
        __builtin_nontemporal_store(o1, (vfloat4*)(out + ob + 4));
    }
}

// ---------------------------------------------------------------------------
extern "C" void kernel_launch(void* const* d_in, const int* in_sizes, int n_in,
                              void* d_out, int out_size, void* d_ws, size_t ws_size,
                              hipStream_t stream) {
    const float* hs       = (const float*)d_in[0];  // [B,S,H]
    const float* wc       = (const float*)d_in[1];  // [R,H]
    const float* bc       = (const float*)d_in[2];  // [R]
    const float* we       = (const float*)d_in[3];  // [R,H]
    const float* be       = (const float*)d_in[4];  // [R,H]
    const float* strength = (const float*)d_in[5];  // [R]
    float* out = (float*)d_out;                     // [B,S,S]

    float* ws    = (float*)d_ws;
    float* besum = ws;                    // 1024
    float* V     = besum + HQ;            // 16384
    float* P     = V + NROWS;             // 16*16384
    float* U     = P + RQ * NROWS;        // 16*16384  (~2.2 MB total)

    besum_kernel<<<dim3(HQ / 256), dim3(256), 0, stream>>>(be, besum);
    proj_kernel<<<dim3(NROWS / 32), dim3(512), 0, stream>>>(hs, wc, we, besum, bc, strength, P, U, V);
    bias_kernel<<<dim3(SQ / 128, SQ / 128, BQ), dim3(256), 0, stream>>>(P, U, V, out);
}

// Round 5
// 345.301 us; speedup vs baseline: 2.2817x; 2.2817x over previous
//
#include <hip/hip_runtime.h>

// Problem constants: B=4, S=4096, H=1024, R=16
#define BQ 4
#define SQ 4096
#define HQ 1024
#define RQ 16
#define NROWS (BQ * SQ)   // 16384

typedef float  f32x16 __attribute__((ext_vector_type(16)));
typedef short  s16x8  __attribute__((ext_vector_type(8)));

__device__ __forceinline__ unsigned short f2bf(float f) {
    union { float f; unsigned int u; } c; c.f = f;
    unsigned int u = c.u + 0x7FFFu + ((c.u >> 16) & 1u);   // RNE
    return (unsigned short)(u >> 16);
}

// ---------------------------------------------------------------------------
// besum[h] = sum_r be[r][h]
// ---------------------------------------------------------------------------
__global__ void besum_kernel(const float* __restrict__ be, float* __restrict__ besum) {
    int h = blockIdx.x * 256 + threadIdx.x;
    float s = 0.f;
#pragma unroll
    for (int r = 0; r < RQ; ++r) s += be[r * HQ + h];
    besum[h] = s;
}

// ---------------------------------------------------------------------------
// proj: [16384 x 1024] x [1024 x 33] -> Pbf[row][16] bf16, Ubf[row][16] bf16,
// V[row] f32.  64-row tiles, 1024 threads = 16 waves, grid (256, 2):
// blockIdx.y = 0 -> P(+V) half, 1 -> U half  => 2 independent blocks/CU.
// wg = wave>>3 takes j 0-7 vs 8-15 of each 64-float K-chunk (WAVE-UNIFORM ->
// weights stay on the scalar path / SGPRs -- the R4 regression was breaking
// this).  w8 = wave&7 owns cols {2w8, 2w8+1} of this half's 16 columns.
// LDS: 64x64 f32 tile double-buffered (32 KB), chunk^(row&7) XOR swizzle,
// ONE barrier per K-chunk (stage-write precedes barrier; fast waves can be
// at most one barrier ahead, so buffer reuse is WAR-safe).
// Epilogue: wg-combine via LDS, fold (dot+bc)*strength, emit bf16 AoS rows.
// ---------------------------------------------------------------------------
__global__ void __launch_bounds__(1024, 8)
proj_kernel(const float* __restrict__ hs, const float* __restrict__ wc,
            const float* __restrict__ we, const float* __restrict__ besum,
            const float* __restrict__ bc, const float* __restrict__ strength,
            unsigned short* __restrict__ Pbf, unsigned short* __restrict__ Ubf,
            float* __restrict__ V) {
    __shared__ float lds[2][64 * 64];   // 32 KB
    const int tid  = threadIdx.x;
    const int lane = tid & 63;
    const int wave = __builtin_amdgcn_readfirstlane(tid >> 6);
    const int wg   = wave >> 3;          // j-half (wave-uniform)
    const int w8   = wave & 7;           // column pair
    const int half = blockIdx.y;         // 0: P+V   1: U
    const int R0   = blockIdx.x * 64;
    const float* wbase = (half ? we : wc) + (2 * w8) * HQ;
    const bool dov = (half == 0) && (w8 == 0);

    // Stage geometry: tile = 64 rows x 16 float4-chunks = 1024 chunks,
    // 1024 threads -> one chunk each, fully coalesced.
    const int r0s = tid >> 4;
    const int m0s = tid & 15;
    const int l0  = r0s * 64 + ((m0s ^ (r0s & 7)) << 2);
    const size_t g0 = (size_t)(R0 + r0s) * HQ + (m0s << 2);
    const int e = lane & 7;

    float acc0 = 0.f, acc1 = 0.f, vacc = 0.f;
    float4 sa = *(const float4*)(hs + g0);

    for (int kc = 0; kc < 16; ++kc) {
        const int k0 = kc * 64;
        float* buf = lds[kc & 1];
        *(float4*)&buf[l0] = sa;
        if (kc < 15) sa = *(const float4*)(hs + g0 + k0 + 64);  // early-issue
        __syncthreads();   // single barrier/iter: dbuf + one-barrier-ahead
#pragma unroll
        for (int jj = 0; jj < 8; ++jj) {
            const int j = wg * 8 + jj;                    // wave-uniform
            const float4 w0 = *(const float4*)(wbase + k0 + 4 * j);
            const float4 w1 = *(const float4*)(wbase + HQ + k0 + 4 * j);
            const float4 h  = *(const float4*)&buf[lane * 64 + ((j ^ e) << 2)];
            acc0 = fmaf(h.x, w0.x, fmaf(h.y, w0.y, fmaf(h.z, w0.z, fmaf(h.w, w0.w, acc0))));
            acc1 = fmaf(h.x, w1.x, fmaf(h.y, w1.y, fmaf(h.z, w1.z, fmaf(h.w, w1.w, acc1))));
            if (dov) {
                const float4 b4 = *(const float4*)(besum + k0 + 4 * j);
                vacc = fmaf(h.x, b4.x, fmaf(h.y, b4.y, fmaf(h.z, b4.z, fmaf(h.w, b4.w, vacc))));
            }
        }
    }
    __syncthreads();   // compute done; reuse LDS for combine

    float* part   = &lds[0][0];     // [8][64][2] = 1024 floats
    float* vpart  = part + 1024;    // [64]
    float* pstage = &lds[1][0];     // [64][16]
    if (wg == 1) {
        part[(w8 * 64 + lane) * 2 + 0] = acc0;
        part[(w8 * 64 + lane) * 2 + 1] = acc1;
        if (dov) vpart[lane] = vacc;
    }
    __syncthreads();
    if (wg == 0) {
        acc0 += part[(w8 * 64 + lane) * 2 + 0];
        acc1 += part[(w8 * 64 + lane) * 2 + 1];
        const int c = 2 * w8;
        if (half == 0) {
            acc0 = (acc0 + bc[c]) * strength[c];
            acc1 = (acc1 + bc[c + 1]) * strength[c + 1];
        }
        pstage[lane * 16 + c]     = acc0;
        pstage[lane * 16 + c + 1] = acc1;
        if (dov) V[R0 + lane] = vacc + vpart[lane];
    }
    __syncthreads();
    if (tid < 128) {   // 2 threads/row, 16 B each: coalesced 4 KB bf16 AoS
        const int row = tid >> 1, hsel = (tid & 1) * 8;
        s16x8 v;
#pragma unroll
        for (int q = 0; q < 8; ++q)
            v[q] = (short)f2bf(pstage[row * 16 + hsel + q]);
        unsigned short* dst = (half ? Ubf : Pbf) + (size_t)(R0 + row) * 16 + hsel;
        *(s16x8*)dst = v;
    }
}

// ---------------------------------------------------------------------------
// bias[b,s,t] = sum_r P[b,s,r]*U[b,t,r] + V[b,t]  via MFMA 32x32x16 bf16.
// K=16 = one MFMA per 32x32 tile.  Block = 256 thr (4 waves) -> 128x128 out:
// wave w owns s-strip w*32; j = 0..3 t-tiles.  A-frag: Pbf[s0+lw][8*lh..+8]
// (16 B coalesced global, L2-resident); B-frag: Ubf[t0+32j+lw][8*lh..+8]
// (B^T convention).  C/D: col=lane&31, row=(r&3)+8*(r>>2)+4*(lane>>5).
// Stores: nontemporal dword, 2x128 B contiguous per instr -> full lines.
// Store-bound target: 268 MB -> ~45-55 us.
// ---------------------------------------------------------------------------
__global__ void __launch_bounds__(256, 4)
bias_kernel(const unsigned short* __restrict__ Pbf,
            const unsigned short* __restrict__ Ubf,
            const float* __restrict__ V, float* __restrict__ out) {
    const int b = blockIdx.z;
    const int tid = threadIdx.x;
    const int wave = tid >> 6, lane = tid & 63;
    const int lw = lane & 31, lh = lane >> 5;
    const int t0 = blockIdx.x * 128;
    const int s0 = blockIdx.y * 128 + wave * 32;
    const size_t rbase = (size_t)b * SQ;

    const s16x8 a = *(const s16x8*)(Pbf + (rbase + s0 + lw) * 16 + lh * 8);
    s16x8 bf[4];
    float v[4];
#pragma unroll
    for (int j = 0; j < 4; ++j) {
        bf[j] = *(const s16x8*)(Ubf + (rbase + t0 + 32 * j + lw) * 16 + lh * 8);
        v[j]  = V[rbase + t0 + 32 * j + lw];
    }
    f32x16 acc0 = {}, acc1 = {}, acc2 = {}, acc3 = {};
    acc0 = __builtin_amdgcn_mfma_f32_32x32x16_bf16(a, bf[0], acc0, 0, 0, 0);
    acc1 = __builtin_amdgcn_mfma_f32_32x32x16_bf16(a, bf[1], acc1, 0, 0, 0);
    acc2 = __builtin_amdgcn_mfma_f32_32x32x16_bf16(a, bf[2], acc2, 0, 0, 0);
    acc3 = __builtin_amdgcn_mfma_f32_32x32x16_bf16(a, bf[3], acc3, 0, 0, 0);

#pragma unroll
    for (int r = 0; r < 16; ++r) {
        const int row = (r & 3) + 8 * (r >> 2) + 4 * lh;
        float* ob = out + (rbase + s0 + row) * SQ + lw;
        __builtin_nontemporal_store(acc0[r] + v[0], ob + t0);
        __builtin_nontemporal_store(acc1[r] + v[1], ob + t0 + 32);
        __builtin_nontemporal_store(acc2[r] + v[2], ob + t0 + 64);
        __builtin_nontemporal_store(acc3[r] + v[3], ob + t0 + 96);
    }
}

// ---------------------------------------------------------------------------
extern "C" void kernel_launch(void* const* d_in, const int* in_sizes, int n_in,
                              void* d_out, int out_size, void* d_ws, size_t ws_size,
                              hipStream_t stream) {
    const float* hs       = (const float*)d_in[0];  // [B,S,H]
    const float* wc       = (const float*)d_in[1];  // [R,H]
    const float* bc       = (const float*)d_in[2];  // [R]
    const float* we       = (const float*)d_in[3];  // [R,H]
    const float* be       = (const float*)d_in[4];  // [R,H]
    const float* strength = (const float*)d_in[5];  // [R]
    float* out = (float*)d_out;                     // [B,S,S]

    float* ws    = (float*)d_ws;
    float* besum = ws;                                    // 1024 f32
    float* V     = ws + HQ;                               // 16384 f32
    unsigned short* Pbf = (unsigned short*)(ws + HQ + NROWS);  // 16384*16 bf16
    unsigned short* Ubf = Pbf + (size_t)NROWS * 16;            // 16384*16 bf16

    besum_kernel<<<dim3(HQ / 256), dim3(256), 0, stream>>>(be, besum);
    proj_kernel<<<dim3(NROWS / 64, 2), dim3(1024), 0, stream>>>(
        hs, wc, we, besum, bc, strength, Pbf, Ubf, V);
    bias_kernel<<<dim3(SQ / 128, SQ / 128, BQ), dim3(256), 0, stream>>>(Pbf, Ubf, V, out);
}